// Round 5
// baseline (230.090 us; speedup 1.0000x reference)
//
#include <hip/hip_runtime.h>
#include <hip/hip_bf16.h>
#include <stdint.h>

#define N_NODES 4096
#define INF_ 512
#define OUTF_ 512

typedef unsigned short u16;
typedef __attribute__((ext_vector_type(8))) short bf16x8;
typedef __attribute__((ext_vector_type(4))) float f32x4;

__device__ __forceinline__ u16 f2bf(float f) {
    union { float f; uint32_t u; } v; v.f = f;
    uint32_t u = v.u;
    uint32_t r = u + 0x7FFFu + ((u >> 16) & 1u);
    return (u16)(r >> 16);
}

__device__ __forceinline__ void async16(const void* gsrc, void* ldst) {
    __builtin_amdgcn_global_load_lds(
        (const __attribute__((address_space(1))) unsigned int*)gsrc,
        (__attribute__((address_space(3))) unsigned int*)ldst,
        16, 0, 0);
}

// ---- convert X -> bf16 row-major, W -> bf16 transposed [OUTF][INF] ----
__global__ void convert_kernel(const float* __restrict__ X, const float* __restrict__ W,
                               u16* __restrict__ Xbf, u16* __restrict__ WT) {
    int tid = blockIdx.x * blockDim.x + threadIdx.x;
    if (tid < N_NODES * INF_) Xbf[tid] = f2bf(X[tid]);
    if (tid < INF_ * OUTF_) {
        int n = tid >> 9, k = tid & 511;
        WT[tid] = f2bf(W[k * OUTF_ + n]);   // WT[n][k] = W[k][n]
    }
}

// ---- gemm1: ST = (X @ W)^T bf16. 64x128 tile, BK=32, 4 waves. (verified R2-R4) ----
__global__ __launch_bounds__(256)
void gemm_support(const u16* __restrict__ A, const u16* __restrict__ B,
                  u16* __restrict__ outT) {
    const int K = 512;
    __shared__ u16 As[64][32];
    __shared__ u16 Bs[128][32];

    const int tid  = threadIdx.x;
    const int lane = tid & 63;
    const int w    = tid >> 6;
    const int wr   = w >> 1;
    const int wc   = w & 1;
    const int brow = blockIdx.x * 64;
    const int bcol = blockIdx.y * 128;

    f32x4 acc[2][4] = {};

    const int srA = w * 16 + (lane >> 2);
    const int srB = w * 32 + (lane >> 2);
    const int sc  = (lane & 3) * 8;

    for (int kt = 0; kt < K; kt += 32) {
        __syncthreads();
        async16(&A[(long)(brow + srA) * K + kt + sc],      &As[w * 16][0]);
        async16(&B[(long)(bcol + srB) * K + kt + sc],      &Bs[w * 32][0]);
        async16(&B[(long)(bcol + srB + 16) * K + kt + sc], &Bs[w * 32 + 16][0]);
        __syncthreads();

        bf16x8 af[2], bfr[4];
#pragma unroll
        for (int m = 0; m < 2; ++m)
            af[m] = *(const bf16x8*)&As[wr * 32 + m * 16 + (lane & 15)][(lane >> 4) * 8];
#pragma unroll
        for (int n = 0; n < 4; ++n)
            bfr[n] = *(const bf16x8*)&Bs[wc * 64 + n * 16 + (lane & 15)][(lane >> 4) * 8];
#pragma unroll
        for (int m = 0; m < 2; ++m)
#pragma unroll
            for (int n = 0; n < 4; ++n)
                acc[m][n] = __builtin_amdgcn_mfma_f32_16x16x32_bf16(af[m], bfr[n], acc[m][n], 0, 0, 0);
    }

#pragma unroll
    for (int m = 0; m < 2; ++m)
#pragma unroll
        for (int n = 0; n < 4; ++n) {
            int col  = bcol + wc * 64 + n * 16 + (lane & 15);
            int row0 = brow + wr * 32 + m * 16 + (lane >> 4) * 4;
#pragma unroll
            for (int r = 0; r < 4; ++r)
                outT[(long)col * N_NODES + row0 + r] = f2bf(acc[m][n][r]);
        }
}

// ---- fused gemm2: out = reshape(E@wq) @ S + bias ----
// 256 blocks x 512 thr; block = 16-row full-width stripe; K=4096.
// Pipeline batch = 16 k: E 4KB + B 16KB staged by global_load_lds into 6
// LDS batch-buffers. Per pair of batches: issue 5 VMEM/wave (uniform),
// compute (MFMA 16x16x32 spanning the 2 batches), s_waitcnt vmcnt(5)
// (keeps next pair's loads in flight ACROSS the raw s_barrier). No
// __syncthreads => no vmcnt(0) drain.
__global__ __launch_bounds__(512, 1)
void fused_gemm2(const float4* __restrict__ E4, const float* __restrict__ wq,
                 const u16* __restrict__ ST, const float* __restrict__ bias,
                 float* __restrict__ out) {
    __shared__ u16    Bs[6][512 * 16];   // 6 x 16 KB
    __shared__ float4 Es[6][16 * 16];    // 6 x 4 KB   (total 120 KB)

    const int tid   = threadIdx.x;
    const int lane  = tid & 63;
    const int w     = tid >> 6;           // 0..7
    const int brow  = blockIdx.x * 16;
    const int nbase = w * 64;

    const float w0 = wq[0], w1 = wq[1], w2 = wq[2], w3 = wq[3];

    // --- E staging (1 async16/wave/pair). wave w stages batch 2*pair + (w>>2),
    //     rows (w&3)*4 + (lane>>4), phys slot lane&15 holds logical k = phys^row.
    const int erow  = (w & 3) * 4 + (lane >> 4);
    const int ekph  = lane & 15;
    const int eklog = (ekph ^ erow) & 15;
    const int epar  = w >> 2;                          // batch parity this wave stages
    const float4* esrc = E4 + (long)(brow + erow) * N_NODES + eklog;
    const int e_ldsb = (w & 3) * 1024;                 // byte offset in Es[buf]

    // --- B staging (4 async16/wave/pair = 2 per batch). instr q=w covers cols
    //     [w*32,+32), q=w+8 covers [256+w*32,+32). 16B half h_phys = lane&1
    //     holds logical half h_phys ^ ((c>>2)&1)  (bank swizzle).
    const int bc0 = w * 32 + (lane >> 1);
    const int bc1 = 256 + w * 32 + (lane >> 1);
    const int hph = lane & 1;
    const long bgo0 = (long)bc0 * N_NODES + (hph ^ ((bc0 >> 2) & 1)) * 8;
    const long bgo1 = (long)bc1 * N_NODES + (hph ^ ((bc1 >> 2) & 1)) * 8;
    const int b_ldsb0 = w * 1024;
    const int b_ldsb1 = (w + 8) * 1024;

    // issue one pair's staging: exactly 5 ordered async16 per wave
    auto issuePair = [&](int p) {
        int be = 2 * p + epar;                          // E batch this wave stages
        int b0 = 2 * p, b1 = 2 * p + 1;
        long se = (long)(be > 255 ? 255 : be) * 16;     // clamp source only
        long s0 = (long)(b0 > 255 ? 255 : b0) * 16;
        long s1 = (long)(b1 > 255 ? 255 : b1) * 16;
        async16(esrc + se,      (char*)&Es[be % 6][0] + e_ldsb);
        async16(ST + bgo0 + s0, (char*)&Bs[b0 % 6][0] + b_ldsb0);
        async16(ST + bgo1 + s0, (char*)&Bs[b0 % 6][0] + b_ldsb1);
        async16(ST + bgo0 + s1, (char*)&Bs[b1 % 6][0] + b_ldsb0);
        async16(ST + bgo1 + s1, (char*)&Bs[b1 % 6][0] + b_ldsb1);
    };

    // prologue: pairs 0,1 in flight; wait pair 0; barrier
    issuePair(0);
    issuePair(1);
    asm volatile("s_waitcnt vmcnt(5)" ::: "memory");
    __builtin_amdgcn_sched_barrier(0);
    __builtin_amdgcn_s_barrier();
    __builtin_amdgcn_sched_barrier(0);

    f32x4 acc[4] = {};
    const int ar  = lane & 15;     // frag row / col-within-frag
    const int ahi = lane >> 4;     // 0..3 : k-octet
    const int hlog = ahi & 1;      // 16B half within a 16-k batch

    for (int p = 0; p < 128; ++p) {
        issuePair(p + 2);          // into bufs freed by pair p-1 (barrier'd)

        const int blo = (2 * p) % 6, bhi = (2 * p + 1) % 6;
        const float4* Eb = (ahi < 2) ? &Es[blo][0] : &Es[bhi][0];
        const u16*    Bb = (ahi < 2) ? &Bs[blo][0] : &Bs[bhi][0];

        // A-frag: lane holds A[ar][k = ahi*8 .. +7]; within-batch logical k
        union { bf16x8 v; __hip_bfloat16 h[8]; } apk;
        const int kb = hlog * 8;
#pragma unroll
        for (int j = 0; j < 8; ++j) {
            int kph = ((kb + j) ^ ar) & 15;
            float4 e = Eb[ar * 16 + kph];
            apk.h[j] = __float2bfloat16(e.x * w0 + e.y * w1 + e.z * w2 + e.w * w3);
        }

#pragma unroll
        for (int n = 0; n < 4; ++n) {
            int c = nbase + n * 16 + ar;
            bf16x8 bf = *(const bf16x8*)&Bb[c * 16 + (hlog ^ ((c >> 2) & 1)) * 8];
            acc[n] = __builtin_amdgcn_mfma_f32_16x16x32_bf16(apk.v, bf, acc[n], 0, 0, 0);
        }

        asm volatile("s_waitcnt vmcnt(5)" ::: "memory");   // pair p+1 ready; p+2 stays in flight
        __builtin_amdgcn_sched_barrier(0);
        __builtin_amdgcn_s_barrier();
        __builtin_amdgcn_sched_barrier(0);
    }

    // epilogue: C/D layout col=lane&15, row=(lane>>4)*4+reg (verified R1-R4)
#pragma unroll
    for (int n = 0; n < 4; ++n) {
        int col  = nbase + n * 16 + ar;
        float bv = bias[col];
#pragma unroll
        for (int r = 0; r < 4; ++r)
            out[(long)(brow + ahi * 4 + r) * OUTF_ + col] = acc[n][r] + bv;
    }
}

extern "C" void kernel_launch(void* const* d_in, const int* in_sizes, int n_in,
                              void* d_out, int out_size, void* d_ws, size_t ws_size,
                              hipStream_t stream) {
    const float* X    = (const float*)d_in[0];
    // d_in[1] = adj, unused by forward
    const float* E    = (const float*)d_in[2];
    const float* W    = (const float*)d_in[3];
    const float* wq   = (const float*)d_in[4];
    const float* bias = (const float*)d_in[5];
    float* out = (float*)d_out;

    char* ws = (char*)d_ws;
    u16* ST  = (u16*)ws;                    // 512 x 4096 bf16 (support^T), 4 MB
    u16* Xbf = (u16*)(ws + (4l << 20));     // 4096 x 512 bf16
    u16* WT  = (u16*)(ws + (8l << 20));     // 512 x 512 bf16

    convert_kernel<<<8192, 256, 0, stream>>>(X, W, Xbf, WT);
    gemm_support<<<dim3(64, 4), 256, 0, stream>>>(Xbf, WT, ST);
    fused_gemm2<<<256, 512, 0, stream>>>((const float4*)E, wq, ST, bias, out);
}

// Round 6
// 185.257 us; speedup vs baseline: 1.2420x; 1.2420x over previous
//
#include <hip/hip_runtime.h>
#include <hip/hip_bf16.h>
#include <stdint.h>

#define N_NODES 4096
#define INF_ 512
#define OUTF_ 512

typedef unsigned short u16;
typedef __attribute__((ext_vector_type(8))) short bf16x8;
typedef __attribute__((ext_vector_type(4))) float f32x4;

__device__ __forceinline__ u16 f2bf(float f) {
    union { float f; uint32_t u; } v; v.f = f;
    uint32_t u = v.u;
    uint32_t r = u + 0x7FFFu + ((u >> 16) & 1u);   // round-to-nearest-even
    return (u16)(r >> 16);
}

__device__ __forceinline__ void async16(const void* gsrc, void* ldst) {
    __builtin_amdgcn_global_load_lds(
        (const __attribute__((address_space(1))) unsigned int*)gsrc,
        (__attribute__((address_space(3))) unsigned int*)ldst,
        16, 0, 0);
}

// ---- convert X -> bf16 row-major, W -> bf16 transposed [OUTF][INF] ----
__global__ void convert_kernel(const float* __restrict__ X, const float* __restrict__ W,
                               u16* __restrict__ Xbf, u16* __restrict__ WT) {
    int tid = blockIdx.x * blockDim.x + threadIdx.x;
    if (tid < N_NODES * INF_) Xbf[tid] = f2bf(X[tid]);
    if (tid < INF_ * OUTF_) {
        int n = tid >> 9, k = tid & 511;
        WT[tid] = f2bf(W[k * OUTF_ + n]);   // WT[n][k] = W[k][n]
    }
}

// ---- gemm1: ST = (X @ W)^T bf16. 64x128 tile, BK=32, 4 waves. (verified R2-R5) ----
__global__ __launch_bounds__(256)
void gemm_support(const u16* __restrict__ A, const u16* __restrict__ B,
                  u16* __restrict__ outT) {
    const int K = 512;
    __shared__ u16 As[64][32];
    __shared__ u16 Bs[128][32];

    const int tid  = threadIdx.x;
    const int lane = tid & 63;
    const int w    = tid >> 6;
    const int wr   = w >> 1;
    const int wc   = w & 1;
    const int brow = blockIdx.x * 64;
    const int bcol = blockIdx.y * 128;

    f32x4 acc[2][4] = {};

    const int srA = w * 16 + (lane >> 2);
    const int srB = w * 32 + (lane >> 2);
    const int sc  = (lane & 3) * 8;

    for (int kt = 0; kt < K; kt += 32) {
        __syncthreads();
        async16(&A[(long)(brow + srA) * K + kt + sc],      &As[w * 16][0]);
        async16(&B[(long)(bcol + srB) * K + kt + sc],      &Bs[w * 32][0]);
        async16(&B[(long)(bcol + srB + 16) * K + kt + sc], &Bs[w * 32 + 16][0]);
        __syncthreads();

        bf16x8 af[2], bfr[4];
#pragma unroll
        for (int m = 0; m < 2; ++m)
            af[m] = *(const bf16x8*)&As[wr * 32 + m * 16 + (lane & 15)][(lane >> 4) * 8];
#pragma unroll
        for (int n = 0; n < 4; ++n)
            bfr[n] = *(const bf16x8*)&Bs[wc * 64 + n * 16 + (lane & 15)][(lane >> 4) * 8];
#pragma unroll
        for (int m = 0; m < 2; ++m)
#pragma unroll
            for (int n = 0; n < 4; ++n)
                acc[m][n] = __builtin_amdgcn_mfma_f32_16x16x32_bf16(af[m], bfr[n], acc[m][n], 0, 0, 0);
    }

#pragma unroll
    for (int m = 0; m < 2; ++m)
#pragma unroll
        for (int n = 0; n < 4; ++n) {
            int col  = bcol + wc * 64 + n * 16 + (lane & 15);
            int row0 = brow + wr * 32 + m * 16 + (lane >> 4) * 4;
#pragma unroll
            for (int r = 0; r < 4; ++r)
                outT[(long)col * N_NODES + row0 + r] = f2bf(acc[m][n][r]);
        }
}

// ---- fused gemm2, split-K: parts[z] = reshape(E@wq)[:, z-chunk] @ S[z-chunk, :] ----
// grid (256 m-stripes, 4 k-splits) = 1024 blocks = 4/CU (TLP hides all stalls).
// Block: 16 rows x 512 cols, K-chunk 1024, 32 steps of BK=32.
// A built from E via reg->dot->swizzled LDS (R4-verified, 0 conflicts; 1KB).
// B direct global->reg from L2-resident ST (no LDS).
__global__ __launch_bounds__(512, 6)
void fused_gemm2(const float4* __restrict__ E4, const float* __restrict__ wq,
                 const u16* __restrict__ ST, float* __restrict__ parts) {
    __shared__ u16 As[16 * 32];   // 1 KB, XOR-swizzled quarters

    const int tid   = threadIdx.x;
    const int lane  = tid & 63;
    const int w     = tid >> 6;              // 0..7
    const int brow  = blockIdx.x * 16;
    const int kt0   = blockIdx.y << 10;      // K-chunk base (elements)
    const int nbase = w * 64;

    const float w0 = wq[0], w1 = wq[1], w2 = wq[2], w3 = wq[3];

    // A staging: thread (srow=tid>>5, sk=tid&31); 16B-quarter q stored at q^((srow>>1)&3)
    const int srow  = tid >> 5;
    const int sk    = tid & 31;
    const int a_off = srow * 64 + (((sk >> 3) ^ ((srow >> 1) & 3)) << 4) + (sk & 7) * 2;
    const float4* eptr = E4 + (long)(brow + srow) * N_NODES + kt0 + sk;

    // A fragment read (swizzled), B fragment bases (direct global)
    const int ar   = lane & 15;
    const int ahi  = lane >> 4;
    const int qsw  = ahi ^ ((ar >> 1) & 3);
    const int a_rd = (ar * 4 + qsw) * 16;

    const u16* bbase[4];
#pragma unroll
    for (int n = 0; n < 4; ++n)
        bbase[n] = ST + (long)(nbase + n * 16 + ar) * N_NODES + kt0 + ahi * 8;

    f32x4 acc[4] = {};
    float4 ecur = eptr[0];

    for (int s = 0; s < 32; ++s) {
        __syncthreads();                              // As free (prev reads done)
        float a = ecur.x * w0 + ecur.y * w1 + ecur.z * w2 + ecur.w * w3;
        *(u16*)((char*)As + a_off) = f2bf(a);
        if (s + 1 < 32) ecur = eptr[(s + 1) * 32];    // prefetch next E
        bf16x8 bfr[4];                                 // B(s) direct from L2
#pragma unroll
        for (int n = 0; n < 4; ++n)
            bfr[n] = *(const bf16x8*)(bbase[n] + s * 32);
        __syncthreads();                              // As visible; drain covers bfr/ecur
        bf16x8 af = *(const bf16x8*)((const char*)As + a_rd);
#pragma unroll
        for (int n = 0; n < 4; ++n)
            acc[n] = __builtin_amdgcn_mfma_f32_16x16x32_bf16(af, bfr[n], acc[n], 0, 0, 0);
    }

    // C/D layout col=lane&15, row=(lane>>4)*4+reg (verified R1-R5)
    float* outP = parts + (long)blockIdx.y * (N_NODES * OUTF_);
#pragma unroll
    for (int n = 0; n < 4; ++n) {
        int col = nbase + n * 16 + ar;
#pragma unroll
        for (int r = 0; r < 4; ++r)
            outP[(long)(brow + ahi * 4 + r) * OUTF_ + col] = acc[n][r];
    }
}

// ---- reduce 4 split-K partials + bias (verified R2) ----
__global__ void reduce_kernel(const float4* __restrict__ part, const float4* __restrict__ bias4,
                              float4* __restrict__ out) {
    const int tid = blockIdx.x * blockDim.x + threadIdx.x;
    const long stride4 = (long)N_NODES * OUTF_ / 4;
    float4 a = part[tid];
    float4 b = part[tid + stride4];
    float4 c = part[tid + 2 * stride4];
    float4 d = part[tid + 3 * stride4];
    float4 bv = bias4[tid & (OUTF_ / 4 - 1)];
    float4 o;
    o.x = a.x + b.x + c.x + d.x + bv.x;
    o.y = a.y + b.y + c.y + d.y + bv.y;
    o.z = a.z + b.z + c.z + d.z + bv.z;
    o.w = a.w + b.w + c.w + d.w + bv.w;
    out[tid] = o;
}

extern "C" void kernel_launch(void* const* d_in, const int* in_sizes, int n_in,
                              void* d_out, int out_size, void* d_ws, size_t ws_size,
                              hipStream_t stream) {
    const float* X    = (const float*)d_in[0];
    // d_in[1] = adj, unused by forward
    const float* E    = (const float*)d_in[2];
    const float* W    = (const float*)d_in[3];
    const float* wq   = (const float*)d_in[4];
    const float* bias = (const float*)d_in[5];
    float* out = (float*)d_out;

    char* ws = (char*)d_ws;
    u16*   ST    = (u16*)ws;                    // 512 x 4096 bf16 (support^T), 4 MB
    u16*   Xbf   = (u16*)(ws + (4l << 20));     // 4096 x 512 bf16
    u16*   WT    = (u16*)(ws + (8l << 20));     // 512 x 512 bf16
    float* parts = (float*)(ws + (9l << 20));   // 4 x 4096 x 512 fp32 (32 MB)

    convert_kernel<<<8192, 256, 0, stream>>>(X, W, Xbf, WT);
    gemm_support<<<dim3(64, 4), 256, 0, stream>>>(Xbf, WT, ST);
    fused_gemm2<<<dim3(256, 4), 512, 0, stream>>>((const float4*)E, wq, ST, parts);
    reduce_kernel<<<2048, 256, 0, stream>>>((const float4*)parts, (const float4*)bias, (float4*)out);
}

// Round 7
// 174.371 us; speedup vs baseline: 1.3195x; 1.0624x over previous
//
#include <hip/hip_runtime.h>
#include <hip/hip_bf16.h>
#include <stdint.h>

#define N_NODES 4096
#define INF_ 512
#define OUTF_ 512

typedef unsigned short u16;
typedef __attribute__((ext_vector_type(8))) short bf16x8;
typedef __attribute__((ext_vector_type(4))) float f32x4;

__device__ __forceinline__ u16 f2bf(float f) {
    union { float f; uint32_t u; } v; v.f = f;
    uint32_t u = v.u;
    uint32_t r = u + 0x7FFFu + ((u >> 16) & 1u);   // round-to-nearest-even
    return (u16)(r >> 16);
}

__device__ __forceinline__ void async16(const void* gsrc, void* ldst) {
    __builtin_amdgcn_global_load_lds(
        (const __attribute__((address_space(1))) unsigned int*)gsrc,
        (__attribute__((address_space(3))) unsigned int*)ldst,
        16, 0, 0);
}

// ---- convert X -> bf16 row-major, W -> bf16 transposed [OUTF][INF] ----
__global__ void convert_kernel(const float* __restrict__ X, const float* __restrict__ W,
                               u16* __restrict__ Xbf, u16* __restrict__ WT) {
    int tid = blockIdx.x * blockDim.x + threadIdx.x;
    if (tid < N_NODES * INF_) Xbf[tid] = f2bf(X[tid]);
    if (tid < INF_ * OUTF_) {
        int n = tid >> 9, k = tid & 511;
        WT[tid] = f2bf(W[k * OUTF_ + n]);   // WT[n][k] = W[k][n]
    }
}

// ---- gemm1: ST = (X @ W)^T bf16. 64x128 tile, BK=32, 4 waves. (verified R2-R6) ----
__global__ __launch_bounds__(256)
void gemm_support(const u16* __restrict__ A, const u16* __restrict__ B,
                  u16* __restrict__ outT) {
    const int K = 512;
    __shared__ u16 As[64][32];
    __shared__ u16 Bs[128][32];

    const int tid  = threadIdx.x;
    const int lane = tid & 63;
    const int w    = tid >> 6;
    const int wr   = w >> 1;
    const int wc   = w & 1;
    const int brow = blockIdx.x * 64;
    const int bcol = blockIdx.y * 128;

    f32x4 acc[2][4] = {};

    const int srA = w * 16 + (lane >> 2);
    const int srB = w * 32 + (lane >> 2);
    const int sc  = (lane & 3) * 8;

    for (int kt = 0; kt < K; kt += 32) {
        __syncthreads();
        async16(&A[(long)(brow + srA) * K + kt + sc],      &As[w * 16][0]);
        async16(&B[(long)(bcol + srB) * K + kt + sc],      &Bs[w * 32][0]);
        async16(&B[(long)(bcol + srB + 16) * K + kt + sc], &Bs[w * 32 + 16][0]);
        __syncthreads();

        bf16x8 af[2], bfr[4];
#pragma unroll
        for (int m = 0; m < 2; ++m)
            af[m] = *(const bf16x8*)&As[wr * 32 + m * 16 + (lane & 15)][(lane >> 4) * 8];
#pragma unroll
        for (int n = 0; n < 4; ++n)
            bfr[n] = *(const bf16x8*)&Bs[wc * 64 + n * 16 + (lane & 15)][(lane >> 4) * 8];
#pragma unroll
        for (int m = 0; m < 2; ++m)
#pragma unroll
            for (int n = 0; n < 4; ++n)
                acc[m][n] = __builtin_amdgcn_mfma_f32_16x16x32_bf16(af[m], bfr[n], acc[m][n], 0, 0, 0);
    }

#pragma unroll
    for (int m = 0; m < 2; ++m)
#pragma unroll
        for (int n = 0; n < 4; ++n) {
            int col  = bcol + wc * 64 + n * 16 + (lane & 15);
            int row0 = brow + wr * 32 + m * 16 + (lane >> 4) * 4;
#pragma unroll
            for (int r = 0; r < 4; ++r)
                outT[(long)col * N_NODES + row0 + r] = f2bf(acc[m][n][r]);
        }
}

// ---- fused gemm2, split-K: parts[z] = reshape(E@wq)[:, zchunk] @ S[zchunk, :] ----
// grid (256 m-stripes, 4 k-splits). Block: 16 rows x 512 cols, K-chunk 1024.
// 4 outer steps of BK=256: E 64KB coalesced -> reg dot -> bf16 ds_write into
// 8x 1KB swizzled sub-tiles (R6-verified layout); E(s+1) prefetched across the
// barrier-free 8-sub MFMA phase (B-frags reg-pipelined from L2-resident ST).
// Only 2 barriers per step (8 per block).
__global__ __launch_bounds__(512, 4)
void fused_gemm2(const float4* __restrict__ E4, const float* __restrict__ wq,
                 const u16* __restrict__ ST, float* __restrict__ parts) {
    __shared__ char As[8192];   // 8 sub-tiles x 1KB, swizzled (R6 layout)

    const int tid   = threadIdx.x;
    const int lane  = tid & 63;
    const int w     = tid >> 6;              // 0..7
    const int brow  = blockIdx.x * 16;
    const int kt0   = blockIdx.y << 10;      // k-chunk base (elements == float4 idx)
    const int nbase = w * 64;

    const float w0 = wq[0], w1 = wq[1], w2 = wq[2], w3 = wq[3];

    // --- E staging role: thread covers col c = tid&255, rows r0+2j (j=0..7) ---
    const int c  = tid & 255;
    const int r0 = tid >> 8;                 // 0 or 1
    const float4* eptr = E4 + (long)(brow + r0) * N_NODES + kt0 + c;
    // LDS write offsets per j (row r = r0+2j), R6-verified swizzle:
    // byte = (c>>5)*1024 + r*64 + (((c>>3&3) ^ ((r>>1)&3))<<4) + (c&7)*2
    int woff[8];
#pragma unroll
    for (int j = 0; j < 8; ++j) {
        int r = r0 + 2 * j;
        woff[j] = (c >> 5) * 1024 + r * 64 + ((((c >> 3) & 3) ^ ((r >> 1) & 3)) << 4) + (c & 7) * 2;
    }

    // --- fragment roles ---
    const int ar   = lane & 15;
    const int ahi  = lane >> 4;
    const int a_rd = (ar * 4 + (ahi ^ ((ar >> 1) & 3))) * 16;   // within sub-tile
    const u16* bcol_[4];
#pragma unroll
    for (int n = 0; n < 4; ++n)
        bcol_[n] = ST + (long)(nbase + n * 16 + ar) * N_NODES + kt0 + ahi * 8;

    f32x4 acc[4] = {};
    float4 er[8];

    // prologue: E(step 0)
#pragma unroll
    for (int j = 0; j < 8; ++j) er[j] = eptr[(long)j * 8192];

    for (int s = 0; s < 4; ++s) {
        __syncthreads();                 // prev A-tile reads done; E loads drained
        // dot + stage A(s)
#pragma unroll
        for (int j = 0; j < 8; ++j) {
            float a = er[j].x * w0 + er[j].y * w1 + er[j].z * w2 + er[j].w * w3;
            *(u16*)(As + woff[j]) = f2bf(a);
        }
        __syncthreads();                 // A(s) visible
        // prefetch E(s+1): in flight across the whole MFMA phase
        if (s < 3) {
#pragma unroll
            for (int j = 0; j < 8; ++j) er[j] = eptr[(long)j * 8192 + (s + 1) * 256];
        }
        // MFMA phase: 8 subs, B reg-pipelined, no barriers
        const int se = s * 256;
        bf16x8 bc[4], bn[4];
#pragma unroll
        for (int n = 0; n < 4; ++n) bc[n] = *(const bf16x8*)(bcol_[n] + se);
#pragma unroll
        for (int sub = 0; sub < 8; ++sub) {
            if (sub < 7) {
#pragma unroll
                for (int n = 0; n < 4; ++n)
                    bn[n] = *(const bf16x8*)(bcol_[n] + se + (sub + 1) * 32);
            }
            bf16x8 af = *(const bf16x8*)(As + sub * 1024 + a_rd);
#pragma unroll
            for (int n = 0; n < 4; ++n)
                acc[n] = __builtin_amdgcn_mfma_f32_16x16x32_bf16(af, bc[n], acc[n], 0, 0, 0);
            if (sub < 7) {
#pragma unroll
                for (int n = 0; n < 4; ++n) bc[n] = bn[n];
            }
        }
    }

    // epilogue: C/D layout col=lane&15, row=(lane>>4)*4+reg (verified R1-R6)
    float* outP = parts + (long)blockIdx.y * (N_NODES * OUTF_);
#pragma unroll
    for (int n = 0; n < 4; ++n) {
        int col = nbase + n * 16 + ar;
#pragma unroll
        for (int r = 0; r < 4; ++r)
            outP[(long)(brow + ahi * 4 + r) * OUTF_ + col] = acc[n][r];
    }
}

// ---- reduce 4 split-K partials + bias (verified R2/R6) ----
__global__ void reduce_kernel(const float4* __restrict__ part, const float4* __restrict__ bias4,
                              float4* __restrict__ out) {
    const int tid = blockIdx.x * blockDim.x + threadIdx.x;
    const long stride4 = (long)N_NODES * OUTF_ / 4;
    float4 a = part[tid];
    float4 b = part[tid + stride4];
    float4 c = part[tid + 2 * stride4];
    float4 d = part[tid + 3 * stride4];
    float4 bv = bias4[tid & (OUTF_ / 4 - 1)];
    float4 o;
    o.x = a.x + b.x + c.x + d.x + bv.x;
    o.y = a.y + b.y + c.y + d.y + bv.y;
    o.z = a.z + b.z + c.z + d.z + bv.z;
    o.w = a.w + b.w + c.w + d.w + bv.w;
    out[tid] = o;
}

extern "C" void kernel_launch(void* const* d_in, const int* in_sizes, int n_in,
                              void* d_out, int out_size, void* d_ws, size_t ws_size,
                              hipStream_t stream) {
    const float* X    = (const float*)d_in[0];
    // d_in[1] = adj, unused by forward
    const float* E    = (const float*)d_in[2];
    const float* W    = (const float*)d_in[3];
    const float* wq   = (const float*)d_in[4];
    const float* bias = (const float*)d_in[5];
    float* out = (float*)d_out;

    char* ws = (char*)d_ws;
    u16*   ST    = (u16*)ws;                    // 512 x 4096 bf16 (support^T), 4 MB
    u16*   Xbf   = (u16*)(ws + (4l << 20));     // 4096 x 512 bf16
    u16*   WT    = (u16*)(ws + (8l << 20));     // 512 x 512 bf16
    float* parts = (float*)(ws + (9l << 20));   // 4 x 4096 x 512 fp32 (32 MB)

    convert_kernel<<<8192, 256, 0, stream>>>(X, W, Xbf, WT);
    gemm_support<<<dim3(64, 4), 256, 0, stream>>>(Xbf, WT, ST);
    fused_gemm2<<<dim3(256, 4), 512, 0, stream>>>((const float4*)E, wq, ST, parts);
    reduce_kernel<<<2048, 256, 0, stream>>>((const float4*)parts, (const float4*)bias, (float4*)out);
}

// Round 8
// 110.280 us; speedup vs baseline: 2.0864x; 1.5812x over previous
//
#include <hip/hip_runtime.h>
#include <hip/hip_bf16.h>
#include <stdint.h>

#define N_NODES 4096
#define INF_ 512
#define OUTF_ 512

typedef unsigned short u16;
typedef __attribute__((ext_vector_type(8))) short bf16x8;
typedef __attribute__((ext_vector_type(4))) float f32x4;

__device__ __forceinline__ u16 f2bf(float f) {
    union { float f; uint32_t u; } v; v.f = f;
    uint32_t u = v.u;
    uint32_t r = u + 0x7FFFu + ((u >> 16) & 1u);   // round-to-nearest-even
    return (u16)(r >> 16);
}
__device__ __forceinline__ float bf2f(u16 h) {
    union { uint32_t u; float f; } v; v.u = ((uint32_t)h) << 16;
    return v.f;
}

__device__ __forceinline__ void async16(const void* gsrc, void* ldst) {
    __builtin_amdgcn_global_load_lds(
        (const __attribute__((address_space(1))) unsigned int*)gsrc,
        (__attribute__((address_space(3))) unsigned int*)ldst,
        16, 0, 0);
}

// ---- fused prep: edge weights (E -> Abf bf16, BW-bound) + X/W converts (R2-proven) ----
__global__ void prep_kernel(const float4* __restrict__ E4, const float* __restrict__ wq,
                            u16* __restrict__ Abf,
                            const float* __restrict__ X, const float* __restrict__ W,
                            u16* __restrict__ Xbf, u16* __restrict__ WT) {
    const int tid = blockIdx.x * blockDim.x + threadIdx.x;
    const float w0 = wq[0], w1 = wq[1], w2 = wq[2], w3 = wq[3];

    if (tid < N_NODES * INF_) Xbf[tid] = f2bf(X[tid]);
    if (tid < INF_ * OUTF_) {
        int n = tid >> 9, k = tid & 511;
        WT[tid] = f2bf(W[k * OUTF_ + n]);   // WT[n][k] = W[k][n]
    }

    const int lane = threadIdx.x & 63;
    const long wave = (long)(tid >> 6);
    const long base = wave * 512;
#pragma unroll
    for (int j = 0; j < 8; ++j) {
        long idx = base + j * 64 + lane;
        float4 e = E4[idx];
        Abf[idx] = f2bf(e.x * w0 + e.y * w1 + e.z * w2 + e.w * w3);
    }
}

// ---- gemm1: ST = (X @ W)^T bf16. 64x128 tile, BK=32, 4 waves. (verified R2-R7) ----
__global__ __launch_bounds__(256)
void gemm_support(const u16* __restrict__ A, const u16* __restrict__ B,
                  u16* __restrict__ outT) {
    const int K = 512;
    __shared__ u16 As[64][32];
    __shared__ u16 Bs[128][32];

    const int tid  = threadIdx.x;
    const int lane = tid & 63;
    const int w    = tid >> 6;
    const int wr   = w >> 1;
    const int wc   = w & 1;
    const int brow = blockIdx.x * 64;
    const int bcol = blockIdx.y * 128;

    f32x4 acc[2][4] = {};

    const int srA = w * 16 + (lane >> 2);
    const int srB = w * 32 + (lane >> 2);
    const int sc  = (lane & 3) * 8;

    for (int kt = 0; kt < K; kt += 32) {
        __syncthreads();
        async16(&A[(long)(brow + srA) * K + kt + sc],      &As[w * 16][0]);
        async16(&B[(long)(bcol + srB) * K + kt + sc],      &Bs[w * 32][0]);
        async16(&B[(long)(bcol + srB + 16) * K + kt + sc], &Bs[w * 32 + 16][0]);
        __syncthreads();

        bf16x8 af[2], bfr[4];
#pragma unroll
        for (int m = 0; m < 2; ++m)
            af[m] = *(const bf16x8*)&As[wr * 32 + m * 16 + (lane & 15)][(lane >> 4) * 8];
#pragma unroll
        for (int n = 0; n < 4; ++n)
            bfr[n] = *(const bf16x8*)&Bs[wc * 64 + n * 16 + (lane & 15)][(lane >> 4) * 8];
#pragma unroll
        for (int m = 0; m < 2; ++m)
#pragma unroll
            for (int n = 0; n < 4; ++n)
                acc[m][n] = __builtin_amdgcn_mfma_f32_16x16x32_bf16(af[m], bfr[n], acc[m][n], 0, 0, 0);
    }

#pragma unroll
    for (int m = 0; m < 2; ++m)
#pragma unroll
        for (int n = 0; n < 4; ++n) {
            int col  = bcol + wc * 64 + n * 16 + (lane & 15);
            int row0 = brow + wr * 32 + m * 16 + (lane >> 4) * 4;
#pragma unroll
            for (int r = 0; r < 4; ++r)
                outT[(long)col * N_NODES + row0 + r] = f2bf(acc[m][n][r]);
        }
}

// ---- gemm2: parts[z] = bf16( Abf[:, zc] @ S[zc, :] ).  128x128 tile (R1-verified
// m97 structure: 16KB staging, 16 MFMA/wave/iter), split-K x8, K-chunk 512. ----
__global__ __launch_bounds__(256)
void gemm2_split(const u16* __restrict__ A, const u16* __restrict__ B,
                 u16* __restrict__ parts) {
    const int K = 4096;
    __shared__ u16 As[128][32];
    __shared__ u16 Bs[128][32];

    const int tid  = threadIdx.x;
    const int lane = tid & 63;
    const int w    = tid >> 6;        // wave 0..3
    const int wr   = w >> 1;
    const int wc   = w & 1;
    const int brow = blockIdx.x * 128;
    const int bcol = blockIdx.y * 128;
    const int kt0  = blockIdx.z * 512;

    f32x4 acc[4][4] = {};

    const int sr = w * 32 + (lane >> 2);
    const int sc = (lane & 3) * 8;

    for (int kt = kt0; kt < kt0 + 512; kt += 32) {
        __syncthreads();
        async16(&A[(long)(brow + sr) * K + kt + sc],      &As[w * 32][0]);
        async16(&A[(long)(brow + sr + 16) * K + kt + sc], &As[w * 32 + 16][0]);
        async16(&B[(long)(bcol + sr) * K + kt + sc],      &Bs[w * 32][0]);
        async16(&B[(long)(bcol + sr + 16) * K + kt + sc], &Bs[w * 32 + 16][0]);
        __syncthreads();

        bf16x8 af[4], bfr[4];
#pragma unroll
        for (int m = 0; m < 4; ++m)
            af[m] = *(const bf16x8*)&As[wr * 64 + m * 16 + (lane & 15)][(lane >> 4) * 8];
#pragma unroll
        for (int n = 0; n < 4; ++n)
            bfr[n] = *(const bf16x8*)&Bs[wc * 64 + n * 16 + (lane & 15)][(lane >> 4) * 8];
#pragma unroll
        for (int m = 0; m < 4; ++m)
#pragma unroll
            for (int n = 0; n < 4; ++n)
                acc[m][n] = __builtin_amdgcn_mfma_f32_16x16x32_bf16(af[m], bfr[n], acc[m][n], 0, 0, 0);
    }

    // epilogue -> bf16 partials. C/D layout col=lane&15, row=(lane>>4)*4+reg (verified R1-R7)
    u16* outP = parts + (long)blockIdx.z * (N_NODES * OUTF_);
#pragma unroll
    for (int m = 0; m < 4; ++m)
#pragma unroll
        for (int n = 0; n < 4; ++n) {
            int col  = bcol + wc * 64 + n * 16 + (lane & 15);
            int row0 = brow + wr * 64 + m * 16 + (lane >> 4) * 4;
#pragma unroll
            for (int r = 0; r < 4; ++r)
                outP[(long)(row0 + r) * OUTF_ + col] = f2bf(acc[m][n][r]);
        }
}

// ---- reduce 8 bf16 split-K partials + bias -> fp32 out ----
__global__ void reduce8_kernel(const u16* __restrict__ parts, const float* __restrict__ bias,
                               float* __restrict__ out) {
    const int t = blockIdx.x * blockDim.x + threadIdx.x;   // 256K threads, 8 elems each
    const long base = (long)t * 8;
    const int col0 = (int)(base & (OUTF_ - 1));
    const long stride = (long)N_NODES * OUTF_;

    float s[8];
#pragma unroll
    for (int j = 0; j < 8; ++j) s[j] = bias[col0 + j];
#pragma unroll
    for (int z = 0; z < 8; ++z) {
        bf16x8 v = *(const bf16x8*)(parts + z * stride + base);
#pragma unroll
        for (int j = 0; j < 8; ++j) s[j] += bf2f((u16)v[j]);
    }
    float4* o4 = (float4*)(out + base);
    o4[0] = make_float4(s[0], s[1], s[2], s[3]);
    o4[1] = make_float4(s[4], s[5], s[6], s[7]);
}

extern "C" void kernel_launch(void* const* d_in, const int* in_sizes, int n_in,
                              void* d_out, int out_size, void* d_ws, size_t ws_size,
                              hipStream_t stream) {
    const float* X    = (const float*)d_in[0];
    // d_in[1] = adj, unused by forward
    const float* E    = (const float*)d_in[2];
    const float* W    = (const float*)d_in[3];
    const float* wq   = (const float*)d_in[4];
    const float* bias = (const float*)d_in[5];
    float* out = (float*)d_out;

    char* ws = (char*)d_ws;
    u16* ST    = (u16*)ws;                     // 512 x 4096 bf16 (support^T), 4 MB
    u16* Xbf   = (u16*)(ws + (4l << 20));      // 4096 x 512 bf16, 4 MB
    u16* WT    = (u16*)(ws + (8l << 20));      // 512 x 512 bf16, 0.5 MB
    u16* Abf   = (u16*)(ws + (9l << 20));      // 4096 x 4096 bf16, 32 MB
    u16* parts = (u16*)(ws + (41l << 20));     // 8 x 4096 x 512 bf16, 32 MB

    // 1) E -> Abf (+ converts), ~47us BW-bound
    prep_kernel<<<8192, 256, 0, stream>>>((const float4*)E, wq, Abf, X, W, Xbf, WT);
    // 2) ST = (X@W)^T bf16, ~5us
    gemm_support<<<dim3(64, 4), 256, 0, stream>>>(Xbf, WT, ST);
    // 3) parts[z] = Abf[:,zc] @ S[zc,:], 1024 blocks (4/CU)
    gemm2_split<<<dim3(32, 4, 8), 256, 0, stream>>>(Abf, ST, parts);
    // 4) out = sum_z parts[z] + bias
    reduce8_kernel<<<1024, 256, 0, stream>>>(parts, bias, out);
}